// Round 1
// baseline (285.732 us; speedup 1.0000x reference)
//
#include <hip/hip_runtime.h>

// ---- problem constants (fixed by setup_inputs) ----
#define CDIM   256
#define NHEADS 8
#define NLEV   4
#define NPTS   4
#define DHEAD  32
#define QTOT   12240
#define HWTOT  12240

// ---------------------------------------------------------------------------
// Generic tiled f32 GEMM with bias:  C[M,N] = A[M,K] @ B[K,N] + bias[N]
// BM=64, BN=64, BK=16, 256 threads, 4x4 micro-tile per thread.
// ---------------------------------------------------------------------------
template<int BM, int BN, int BK, int TM, int TN>
__global__ __launch_bounds__(256) void gemm_bias(
    const float* __restrict__ A, const float* __restrict__ B,
    const float* __restrict__ bias, float* __restrict__ Cmat,
    int M, int N, int K)
{
    __shared__ float As[BK][BM + 1];
    __shared__ float Bs[BK][BN + 1];

    const int tid = threadIdx.x;
    const int bm = blockIdx.y * BM;
    const int bn = blockIdx.x * BN;

    constexpr int TX = BN / TN;                 // threads along N (16)
    const int tn = (tid % TX) * TN;
    const int tm = (tid / TX) * TM;

    float acc[TM][TN];
#pragma unroll
    for (int i = 0; i < TM; ++i)
#pragma unroll
        for (int j = 0; j < TN; ++j) acc[i][j] = 0.f;

    for (int k0 = 0; k0 < K; k0 += BK) {
        // stage A tile (transposed so m is stride-1 in LDS)
#pragma unroll
        for (int i = tid; i < BM * BK; i += 256) {
            int m = i / BK, k = i % BK;
            As[k][m] = (bm + m < M) ? A[(size_t)(bm + m) * K + k0 + k] : 0.f;
        }
        // stage B tile
#pragma unroll
        for (int i = tid; i < BK * BN; i += 256) {
            int k = i / BN, n = i % BN;
            Bs[k][n] = B[(size_t)(k0 + k) * N + bn + n];
        }
        __syncthreads();
#pragma unroll
        for (int k = 0; k < BK; ++k) {
            float a[TM], b[TN];
#pragma unroll
            for (int i = 0; i < TM; ++i) a[i] = As[k][tm + i];
#pragma unroll
            for (int j = 0; j < TN; ++j) b[j] = Bs[k][tn + j];
#pragma unroll
            for (int i = 0; i < TM; ++i)
#pragma unroll
                for (int j = 0; j < TN; ++j) acc[i][j] += a[i] * b[j];
        }
        __syncthreads();
    }

#pragma unroll
    for (int i = 0; i < TM; ++i) {
        int m = bm + tm + i;
        if (m >= M) continue;
#pragma unroll
        for (int j = 0; j < TN; ++j) {
            int n = bn + tn + j;
            Cmat[(size_t)m * N + n] = acc[i][j] + bias[n];
        }
    }
}

// ---------------------------------------------------------------------------
// Fused softmax + bilinear deformable sampling.
// One block (256 threads) per query q.  8 head-groups of 32 lanes; lane = d.
// ---------------------------------------------------------------------------
__global__ __launch_bounds__(256) void sample_kernel(
    const float* __restrict__ rp,      // (Q, LEVELS, 2)
    const float* __restrict__ off,     // (Q, 256) = (H,L,P,2)
    const float* __restrict__ logits,  // (Q, 128) = (H,L*P)
    const float* __restrict__ proj,    // (HW, 256) value projection
    const int*   __restrict__ sp,      // (LEVELS,2) = (H,W)
    const int*   __restrict__ lsi,     // (LEVELS,)
    float* __restrict__ outp)          // (Q, 256)
{
    const int q = blockIdx.x;
    const int tid = threadIdx.x;

    __shared__ float s_off[256];
    __shared__ float s_attn[128];

    s_off[tid] = off[(size_t)q * 256 + tid];
    if (tid < 128) s_attn[tid] = logits[(size_t)q * 128 + tid];
    __syncthreads();

    if (tid < NHEADS) {
        // softmax over 16 values per head (serial per head; trivial cost)
        float m = -1e30f;
#pragma unroll
        for (int i = 0; i < 16; ++i) m = fmaxf(m, s_attn[tid * 16 + i]);
        float e[16];
        float s = 0.f;
#pragma unroll
        for (int i = 0; i < 16; ++i) { e[i] = __expf(s_attn[tid * 16 + i] - m); s += e[i]; }
        float inv = 1.f / s;
#pragma unroll
        for (int i = 0; i < 16; ++i) s_attn[tid * 16 + i] = e[i] * inv;
    }
    __syncthreads();

    const int h = tid >> 5;    // head
    const int d = tid & 31;    // channel within head

    float acc = 0.f;

#pragma unroll
    for (int l = 0; l < NLEV; ++l) {
        const int Hl = sp[l * 2 + 0];
        const int Wl = sp[l * 2 + 1];
        const int st = lsi[l];
        const float rx = rp[((size_t)q * NLEV + l) * 2 + 0];
        const float ry = rp[((size_t)q * NLEV + l) * 2 + 1];
        const float* base = proj + (size_t)st * CDIM + h * DHEAD + d;

#pragma unroll
        for (int p = 0; p < NPTS; ++p) {
            const int oi = ((h * NLEV + l) * NPTS + p) * 2;
            const float x = rx * (float)Wl + s_off[oi + 0] - 0.5f;
            const float y = ry * (float)Hl + s_off[oi + 1] - 0.5f;
            const float aw = s_attn[h * 16 + l * NPTS + p];

            const float xf = floorf(x), yf = floorf(y);
            const int x0 = (int)xf, y0 = (int)yf;
            const float lx = x - xf, ly = y - yf;

            const float w00 = (1.f - ly) * (1.f - lx);
            const float w01 = (1.f - ly) * lx;
            const float w10 = ly * (1.f - lx);
            const float w11 = ly * lx;

            const bool vx0 = (x0 >= 0) && (x0 < Wl);
            const bool vx1 = (x0 + 1 >= 0) && (x0 + 1 < Wl);
            const bool vy0 = (y0 >= 0) && (y0 < Hl);
            const bool vy1 = (y0 + 1 >= 0) && (y0 + 1 < Hl);

            float v00 = (vx0 && vy0) ? base[(size_t)(y0 * Wl + x0) * CDIM] : 0.f;
            float v01 = (vx1 && vy0) ? base[(size_t)(y0 * Wl + x0 + 1) * CDIM] : 0.f;
            float v10 = (vx0 && vy1) ? base[(size_t)((y0 + 1) * Wl + x0) * CDIM] : 0.f;
            float v11 = (vx1 && vy1) ? base[(size_t)((y0 + 1) * Wl + x0 + 1) * CDIM] : 0.f;

            acc += aw * (w00 * v00 + w01 * v01 + w10 * v10 + w11 * v11);
        }
    }

    outp[(size_t)q * CDIM + h * DHEAD + d] = acc;
}

// ---------------------------------------------------------------------------
extern "C" void kernel_launch(void* const* d_in, const int* in_sizes, int n_in,
                              void* d_out, int out_size, void* d_ws, size_t ws_size,
                              hipStream_t stream) {
    const float* query  = (const float*)d_in[0];
    const float* rp     = (const float*)d_in[1];
    const float* inflat = (const float*)d_in[2];
    const int*   sp     = (const int*)d_in[3];
    const int*   lsi    = (const int*)d_in[4];
    const float* W_off  = (const float*)d_in[5];
    const float* b_off  = (const float*)d_in[6];
    const float* W_attn = (const float*)d_in[7];
    const float* b_attn = (const float*)d_in[8];
    const float* W_val  = (const float*)d_in[9];
    const float* b_val  = (const float*)d_in[10];
    const float* W_out  = (const float*)d_in[11];
    const float* b_out  = (const float*)d_in[12];
    float* out = (float*)d_out;

    // workspace layout
    float* proj    = (float*)d_ws;                       // HW*256
    float* offbuf  = proj   + (size_t)HWTOT * CDIM;      // Q*256
    float* logits  = offbuf + (size_t)QTOT * CDIM;       // Q*128
    float* outpre  = logits + (size_t)QTOT * 128;        // Q*256

    constexpr int BM = 64, BN = 64, BK = 16, TM = 4, TN = 4;
    dim3 blk(256);
    dim3 gA(CDIM / BN, (HWTOT + BM - 1) / BM);   // value proj: N=256
    dim3 gO(CDIM / BN, (QTOT + BM - 1) / BM);    // offsets:    N=256
    dim3 gL(128 / BN,  (QTOT + BM - 1) / BM);    // logits:     N=128
    dim3 gF(CDIM / BN, (QTOT + BM - 1) / BM);    // final:      N=256

    // 1. value projection
    gemm_bias<BM, BN, BK, TM, TN><<<gA, blk, 0, stream>>>(
        inflat, W_val, b_val, proj, HWTOT, CDIM, CDIM);

    // 2. offset / attention-logit projections
    gemm_bias<BM, BN, BK, TM, TN><<<gO, blk, 0, stream>>>(
        query, W_off, b_off, offbuf, QTOT, CDIM, CDIM);
    gemm_bias<BM, BN, BK, TM, TN><<<gL, blk, 0, stream>>>(
        query, W_attn, b_attn, logits, QTOT, 128, CDIM);

    // 3. softmax + deformable bilinear sampling
    sample_kernel<<<dim3(QTOT), blk, 0, stream>>>(
        rp, offbuf, logits, proj, sp, lsi, outpre);

    // 4. output projection
    gemm_bias<BM, BN, BK, TM, TN><<<gF, blk, 0, stream>>>(
        outpre, W_out, b_out, out, QTOT, CDIM, CDIM);
}

// Round 2
// 83.476 us; speedup vs baseline: 3.4229x; 3.4229x over previous
//
#include <hip/hip_runtime.h>

// ---- problem constants ----
#define CDIM   256
#define NHEADS 8
#define NLEV   4
#define NPTS   4
#define QTOT   12240
#define HWTOT  12240
#define KDIM   256

typedef float  f32x4 __attribute__((ext_vector_type(4)));
typedef short  s16x8 __attribute__((ext_vector_type(8)));

__device__ __forceinline__ unsigned short f2b(float x) {
    union { float f; unsigned u; } c; c.f = x;
    unsigned r = c.u + 0x7fffu + ((c.u >> 16) & 1u);
    return (unsigned short)(r >> 16);
}

// ---------------------------------------------------------------------------
// Prep: transpose+convert weights to bf16 [N][K], build combined off/attn
// weight (N=384) and combined bias.
// ---------------------------------------------------------------------------
__global__ __launch_bounds__(256) void prep_kernel(
    const float* __restrict__ W_val, const float* __restrict__ W_off,
    const float* __restrict__ W_attn, const float* __restrict__ W_out,
    const float* __restrict__ b_off, const float* __restrict__ b_attn,
    unsigned short* __restrict__ WvT, unsigned short* __restrict__ WcT,
    unsigned short* __restrict__ WoT, float* __restrict__ bcomb)
{
    int id = blockIdx.x * 256 + threadIdx.x;
    if (id < 65536) {                               // WvT[n][k] = W_val[k][n]
        int n = id >> 8, k = id & 255;
        WvT[id] = f2b(W_val[k * 256 + n]);
    } else if (id < 65536 + 98304) {                // WcT[n][k], n<256: W_off, else W_attn
        int t = id - 65536;
        int n = t >> 8, k = t & 255;
        float v = (n < 256) ? W_off[k * 256 + n] : W_attn[k * 128 + (n - 256)];
        WcT[t] = f2b(v);
    } else if (id < 65536 + 98304 + 65536) {        // WoT[n][k] = W_out[k][n]
        int t = id - 163840;
        int n = t >> 8, k = t & 255;
        WoT[t] = f2b(W_out[k * 256 + n]);
    } else if (id < 229376 + 384) {                 // combined bias
        int t = id - 229376;
        bcomb[t] = (t < 256) ? b_off[t] : b_attn[t - 256];
    }
}

// ---------------------------------------------------------------------------
// bf16 MFMA GEMM:  C[M,N] = A[M,K=256] @ BT[N,K]^T + bias[N]
// Tile 128x64, BK=32, 4 waves (2x2), each wave 64x32 via 4x2 16x16x32 frags.
// A source is f32 (converted on the fly) or bf16. Output f32 or bf16.
// ---------------------------------------------------------------------------
template<bool A_BF16, bool STORE_BF16>
__global__ __launch_bounds__(256) void gemm_mfma(
    const void* __restrict__ Aptr, const unsigned short* __restrict__ BT,
    const float* __restrict__ bias, void* __restrict__ Cptr, int M, int N)
{
    constexpr int BM = 128, BN = 64, BK = 32;
    __shared__ unsigned short As[BM][40];   // pad to 40 (80B stride, 16B-aligned rows)
    __shared__ unsigned short Bs[BN][40];

    const int tid  = threadIdx.x;
    const int lane = tid & 63;
    const int wave = tid >> 6;
    const int bm = blockIdx.y * BM, bn = blockIdx.x * BN;
    const int wr = wave >> 1, wc = wave & 1;

    f32x4 acc[4][2];
#pragma unroll
    for (int m = 0; m < 4; ++m)
#pragma unroll
        for (int n = 0; n < 2; ++n) acc[m][n] = (f32x4)0.f;

    const int arow = tid >> 1, akseg = (tid & 1) * 16;
    const int brow = tid >> 2, bkseg = (tid & 3) * 8;
    const bool aval = (bm + arow) < M;

    for (int k0 = 0; k0 < KDIM; k0 += BK) {
        // ---- stage A tile (128 x 32) ----
        if constexpr (A_BF16) {
            const unsigned short* A = (const unsigned short*)Aptr;
            s16x8 v0 = (s16x8)0, v1 = (s16x8)0;
            if (aval) {
                const s16x8* src = (const s16x8*)(A + (size_t)(bm + arow) * KDIM + k0 + akseg);
                v0 = src[0]; v1 = src[1];
            }
            *(s16x8*)&As[arow][akseg]     = v0;
            *(s16x8*)&As[arow][akseg + 8] = v1;
        } else {
            const float* A = (const float*)Aptr;
            float4 f0 = {}, f1 = {}, f2 = {}, f3 = {};
            if (aval) {
                const float4* src = (const float4*)(A + (size_t)(bm + arow) * KDIM + k0 + akseg);
                f0 = src[0]; f1 = src[1]; f2 = src[2]; f3 = src[3];
            }
            s16x8 v0, v1;
            v0[0]=f2b(f0.x); v0[1]=f2b(f0.y); v0[2]=f2b(f0.z); v0[3]=f2b(f0.w);
            v0[4]=f2b(f1.x); v0[5]=f2b(f1.y); v0[6]=f2b(f1.z); v0[7]=f2b(f1.w);
            v1[0]=f2b(f2.x); v1[1]=f2b(f2.y); v1[2]=f2b(f2.z); v1[3]=f2b(f2.w);
            v1[4]=f2b(f3.x); v1[5]=f2b(f3.y); v1[6]=f2b(f3.z); v1[7]=f2b(f3.w);
            *(s16x8*)&As[arow][akseg]     = v0;
            *(s16x8*)&As[arow][akseg + 8] = v1;
        }
        // ---- stage B tile (64 n-rows x 32 k), source already [N][K] bf16 ----
        {
            const s16x8* src = (const s16x8*)(BT + (size_t)(bn + brow) * KDIM + k0 + bkseg);
            *(s16x8*)&Bs[brow][bkseg] = *src;
        }
        __syncthreads();

        const int lr = lane & 15, g8 = (lane >> 4) * 8;
        s16x8 af[4], bf[2];
#pragma unroll
        for (int m = 0; m < 4; ++m)
            af[m] = *(const s16x8*)&As[wr * 64 + m * 16 + lr][g8];
#pragma unroll
        for (int n = 0; n < 2; ++n)
            bf[n] = *(const s16x8*)&Bs[wc * 32 + n * 16 + lr][g8];
#pragma unroll
        for (int m = 0; m < 4; ++m)
#pragma unroll
            for (int n = 0; n < 2; ++n)
                acc[m][n] = __builtin_amdgcn_mfma_f32_16x16x32_bf16(af[m], bf[n], acc[m][n], 0, 0, 0);
        __syncthreads();
    }

    // ---- epilogue: C/D layout col=lane&15, row=(lane>>4)*4+reg ----
    const int lr = lane & 15, rg = (lane >> 4) * 4;
#pragma unroll
    for (int n = 0; n < 2; ++n) {
        const int col = bn + wc * 32 + n * 16 + lr;
        const float bb = bias[col];
#pragma unroll
        for (int m = 0; m < 4; ++m) {
#pragma unroll
            for (int r = 0; r < 4; ++r) {
                const int row = bm + wr * 64 + m * 16 + rg + r;
                if (row < M) {
                    float v = acc[m][n][r] + bb;
                    if constexpr (STORE_BF16)
                        ((unsigned short*)Cptr)[(size_t)row * N + col] = f2b(v);
                    else
                        ((float*)Cptr)[(size_t)row * N + col] = v;
                }
            }
        }
    }
}

// ---------------------------------------------------------------------------
// Fused softmax + bilinear sampling.
// Block = 1 query, 256 threads. Phase 1: 128 threads compute per-(head,point)
// metadata (softmax weight folded into 4 corner weights + 4 clamped indices)
// into LDS. Phase 2: 8 groups of 32 lanes; lane owns 2 bf16 channels; the two
// 16-lane halves split the 16 points, reduced with shfl_xor(16).
// ---------------------------------------------------------------------------
__global__ __launch_bounds__(256) void sample_kernel2(
    const float* __restrict__ rp,       // (Q,4,2)
    const float* __restrict__ offlog,   // (Q,384): [0:256]=offsets, [256:384]=logits
    const unsigned short* __restrict__ projb, // (HW,256) bf16
    const int* __restrict__ sp, const int* __restrict__ lsi,
    unsigned short* __restrict__ outpre)      // (Q,256) bf16
{
    const int bid = blockIdx.x;
    const int q = (bid & 7) * (QTOT / 8) + (bid >> 3);   // XCD-chunked swizzle
    const int tid = threadIdx.x;

    __shared__ int   s_idx[128][4];
    __shared__ float s_w[128][4];

    if (tid < 128) {
        const int i = tid & 15, l = i >> 2;
        float logit = offlog[(size_t)q * 384 + 256 + tid];
        float mx = logit;
#pragma unroll
        for (int d = 1; d < 16; d <<= 1) mx = fmaxf(mx, __shfl_xor(mx, d));
        float e = __expf(logit - mx);
        float s = e;
#pragma unroll
        for (int d = 1; d < 16; d <<= 1) s += __shfl_xor(s, d);
        const float aw = e / s;

        const float ox = offlog[(size_t)q * 384 + tid * 2 + 0];
        const float oy = offlog[(size_t)q * 384 + tid * 2 + 1];
        const int Hl = sp[l * 2], Wl = sp[l * 2 + 1], st = lsi[l];
        const float rx = rp[((size_t)q * 4 + l) * 2 + 0];
        const float ry = rp[((size_t)q * 4 + l) * 2 + 1];

        const float x = rx * (float)Wl + ox - 0.5f;
        const float y = ry * (float)Hl + oy - 0.5f;
        const float xf = floorf(x), yf = floorf(y);
        const int x0 = (int)xf, y0 = (int)yf;
        const float lx = x - xf, ly = y - yf;

        const bool vx0 = (x0 >= 0) && (x0 < Wl);
        const bool vx1 = (x0 + 1 >= 0) && (x0 + 1 < Wl);
        const bool vy0 = (y0 >= 0) && (y0 < Hl);
        const bool vy1 = (y0 + 1 >= 0) && (y0 + 1 < Hl);

        s_w[tid][0] = (vx0 && vy0) ? aw * (1.f - ly) * (1.f - lx) : 0.f;
        s_w[tid][1] = (vx1 && vy0) ? aw * (1.f - ly) * lx         : 0.f;
        s_w[tid][2] = (vx0 && vy1) ? aw * ly * (1.f - lx)         : 0.f;
        s_w[tid][3] = (vx1 && vy1) ? aw * ly * lx                 : 0.f;
        s_idx[tid][0] = (vx0 && vy0) ? st + y0 * Wl + x0           : 0;
        s_idx[tid][1] = (vx1 && vy0) ? st + y0 * Wl + x0 + 1       : 0;
        s_idx[tid][2] = (vx0 && vy1) ? st + (y0 + 1) * Wl + x0     : 0;
        s_idx[tid][3] = (vx1 && vy1) ? st + (y0 + 1) * Wl + x0 + 1 : 0;
    }
    __syncthreads();

    const int h = tid >> 5, half = (tid >> 4) & 1, c2 = tid & 15;
    const unsigned short* base = projb + h * 32 + c2 * 2;

    float ax = 0.f, ay = 0.f;
#pragma unroll
    for (int p = 0; p < 8; ++p) {
        const int slot = h * 16 + half * 8 + p;
        const int4   id4 = *(const int4*)s_idx[slot];
        const float4 w4  = *(const float4*)s_w[slot];
        const unsigned v0 = *(const unsigned*)(base + (size_t)id4.x * 256);
        const unsigned v1 = *(const unsigned*)(base + (size_t)id4.y * 256);
        const unsigned v2 = *(const unsigned*)(base + (size_t)id4.z * 256);
        const unsigned v3 = *(const unsigned*)(base + (size_t)id4.w * 256);
        ax += w4.x * __uint_as_float(v0 << 16);
        ay += w4.x * __uint_as_float(v0 & 0xffff0000u);
        ax += w4.y * __uint_as_float(v1 << 16);
        ay += w4.y * __uint_as_float(v1 & 0xffff0000u);
        ax += w4.z * __uint_as_float(v2 << 16);
        ay += w4.z * __uint_as_float(v2 & 0xffff0000u);
        ax += w4.w * __uint_as_float(v3 << 16);
        ay += w4.w * __uint_as_float(v3 & 0xffff0000u);
    }
    ax += __shfl_xor(ax, 16);
    ay += __shfl_xor(ay, 16);
    if (half == 0) {
        unsigned pk = (unsigned)f2b(ax) | ((unsigned)f2b(ay) << 16);
        *(unsigned*)&outpre[(size_t)q * 256 + h * 32 + c2 * 2] = pk;
    }
}

// ---------------------------------------------------------------------------
extern "C" void kernel_launch(void* const* d_in, const int* in_sizes, int n_in,
                              void* d_out, int out_size, void* d_ws, size_t ws_size,
                              hipStream_t stream) {
    const float* query  = (const float*)d_in[0];
    const float* rp     = (const float*)d_in[1];
    const float* inflat = (const float*)d_in[2];
    const int*   sp     = (const int*)d_in[3];
    const int*   lsi    = (const int*)d_in[4];
    const float* W_off  = (const float*)d_in[5];
    const float* b_off  = (const float*)d_in[6];
    const float* W_attn = (const float*)d_in[7];
    const float* b_attn = (const float*)d_in[8];
    const float* W_val  = (const float*)d_in[9];
    const float* b_val  = (const float*)d_in[10];
    const float* W_out  = (const float*)d_in[11];
    const float* b_out  = (const float*)d_in[12];
    float* out = (float*)d_out;

    char* ws = (char*)d_ws;
    unsigned short* projb  = (unsigned short*)ws; ws += (size_t)QTOT * 256 * 2;
    float*          offlog = (float*)ws;          ws += (size_t)QTOT * 384 * 4;
    unsigned short* outpre = (unsigned short*)ws; ws += (size_t)QTOT * 256 * 2;
    unsigned short* WvT    = (unsigned short*)ws; ws += 65536 * 2;
    unsigned short* WcT    = (unsigned short*)ws; ws += 98304 * 2;
    unsigned short* WoT    = (unsigned short*)ws; ws += 65536 * 2;
    float*          bcomb  = (float*)ws;          ws += 384 * 4;

    dim3 blk(256);

    prep_kernel<<<dim3((229760 + 255) / 256), blk, 0, stream>>>(
        W_val, W_off, W_attn, W_out, b_off, b_attn, WvT, WcT, WoT, bcomb);

    // value projection -> bf16
    gemm_mfma<false, true><<<dim3(256 / 64, (HWTOT + 127) / 128), blk, 0, stream>>>(
        inflat, WvT, b_val, projb, HWTOT, 256);

    // combined offset+logit projection -> f32
    gemm_mfma<false, false><<<dim3(384 / 64, (QTOT + 127) / 128), blk, 0, stream>>>(
        query, WcT, bcomb, offlog, QTOT, 384);

    // softmax + deformable sampling -> bf16
    sample_kernel2<<<dim3(QTOT), blk, 0, stream>>>(rp, offlog, projb, sp, lsi, outpre);

    // output projection -> f32
    gemm_mfma<true, false><<<dim3(256 / 64, (QTOT + 127) / 128), blk, 0, stream>>>(
        outpre, WoT, b_out, out, QTOT, 256);
}

// Round 3
// 72.952 us; speedup vs baseline: 3.9167x; 1.1443x over previous
//
#include <hip/hip_runtime.h>

// ---- problem constants ----
#define QTOT   12240
#define HWTOT  12240
#define KDIM   256

typedef float f32x4 __attribute__((ext_vector_type(4)));
typedef short s16x8 __attribute__((ext_vector_type(8)));
typedef unsigned short ushort_t;

__device__ __forceinline__ unsigned short f2b(float x) {
    union { float f; unsigned u; } c; c.f = x;
    unsigned r = c.u + 0x7fffu + ((c.u >> 16) & 1u);
    return (unsigned short)(r >> 16);
}

// ---------------------------------------------------------------------------
// One-shot conversion pass: inflat/query f32 -> bf16 (vectorized), weights
// transposed+converted to bf16 [N][K], combined off/attn bias.
// ---------------------------------------------------------------------------
#define AEL 783360              // 12240*256/4
__global__ __launch_bounds__(256) void conv_kernel(
    const float* __restrict__ inflat, const float* __restrict__ query,
    const float* __restrict__ W_val, const float* __restrict__ W_off,
    const float* __restrict__ W_attn, const float* __restrict__ W_out,
    const float* __restrict__ b_off, const float* __restrict__ b_attn,
    ushort_t* __restrict__ inflat_b, ushort_t* __restrict__ query_b,
    ushort_t* __restrict__ WvT, ushort_t* __restrict__ WcT,
    ushort_t* __restrict__ WoT, float* __restrict__ bcomb)
{
    int id = blockIdx.x * 256 + threadIdx.x;
    if (id < 2 * AEL) {
        const float* src = (id < AEL) ? inflat : query;
        ushort_t* dst = (id < AEL) ? inflat_b : query_b;
        int t = (id < AEL) ? id : id - AEL;
        float4 f = ((const float4*)src)[t];
        ushort4 o;
        o.x = f2b(f.x); o.y = f2b(f.y); o.z = f2b(f.z); o.w = f2b(f.w);
        ((ushort4*)dst)[t] = o;
    } else if (id < 2 * AEL + 65536) {               // WvT[n][k] = W_val[k][n]
        int t = id - 2 * AEL;
        int n = t >> 8, k = t & 255;
        WvT[t] = f2b(W_val[k * 256 + n]);
    } else if (id < 2 * AEL + 65536 + 98304) {       // WcT: n<256 W_off else W_attn
        int t = id - (2 * AEL + 65536);
        int n = t >> 8, k = t & 255;
        float v = (n < 256) ? W_off[k * 256 + n] : W_attn[k * 128 + (n - 256)];
        WcT[t] = f2b(v);
    } else if (id < 2 * AEL + 65536 + 98304 + 65536) { // WoT[n][k] = W_out[k][n]
        int t = id - (2 * AEL + 65536 + 98304);
        int n = t >> 8, k = t & 255;
        WoT[t] = f2b(W_out[k * 256 + n]);
    } else if (id < 2 * AEL + 229376 + 384) {
        int t = id - (2 * AEL + 229376);
        bcomb[t] = (t < 256) ? b_off[t] : b_attn[t - 256];
    }
}

// ---------------------------------------------------------------------------
// Shared MFMA core: 64x64 tile, BK=64, K=256, 4 waves (2x2), each wave 32x32.
// Global loads for iter k are issued BEFORE the barrier that closes iter k-1
// (latency hides under previous MFMA phase).
// ---------------------------------------------------------------------------
__device__ __forceinline__ void mm_core(
    const ushort_t* __restrict__ A, const ushort_t* __restrict__ BT,
    int bm, int bn, ushort_t As[64][72], ushort_t Bs[64][72], f32x4 acc[2][2])
{
    const int tid = threadIdx.x, lane = tid & 63, wave = tid >> 6;
    const int wr = wave >> 1, wc = wave & 1;
    const int r = tid >> 2, ks = (tid & 3) * 16;
    const bool aval = (bm + r) < QTOT;
    const int lr = lane & 15, g8 = (lane >> 4) * 8;

    for (int k0 = 0; k0 < KDIM; k0 += 64) {
        s16x8 a0 = (s16x8)0, a1 = (s16x8)0;
        if (aval) {
            const s16x8* s = (const s16x8*)(A + (size_t)(bm + r) * KDIM + k0 + ks);
            a0 = s[0]; a1 = s[1];
        }
        const s16x8* t = (const s16x8*)(BT + (size_t)(bn + r) * KDIM + k0 + ks);
        s16x8 b0 = t[0], b1 = t[1];
        if (k0) __syncthreads();           // previous iter's compute done
        *(s16x8*)&As[r][ks]     = a0;
        *(s16x8*)&As[r][ks + 8] = a1;
        *(s16x8*)&Bs[r][ks]     = b0;
        *(s16x8*)&Bs[r][ks + 8] = b1;
        __syncthreads();
#pragma unroll
        for (int kk = 0; kk < 2; ++kk) {
            s16x8 af[2], bf[2];
            af[0] = *(const s16x8*)&As[wr * 32 + lr][kk * 32 + g8];
            af[1] = *(const s16x8*)&As[wr * 32 + 16 + lr][kk * 32 + g8];
            bf[0] = *(const s16x8*)&Bs[wc * 32 + lr][kk * 32 + g8];
            bf[1] = *(const s16x8*)&Bs[wc * 32 + 16 + lr][kk * 32 + g8];
#pragma unroll
            for (int m = 0; m < 2; ++m)
#pragma unroll
                for (int n = 0; n < 2; ++n)
                    acc[m][n] = __builtin_amdgcn_mfma_f32_16x16x32_bf16(
                        af[m], bf[n], acc[m][n], 0, 0, 0);
        }
    }
}

// Fused value-proj (blocks 0..767) + off/attn-proj (blocks 768..1919).
__global__ __launch_bounds__(256) void gemm_vc(
    const ushort_t* __restrict__ Ab, const ushort_t* __restrict__ Qb,
    const ushort_t* __restrict__ WvT, const ushort_t* __restrict__ WcT,
    const float* __restrict__ b_val, const float* __restrict__ bcomb,
    ushort_t* __restrict__ projb, ushort_t* __restrict__ offb,
    float* __restrict__ logitf)
{
    __shared__ ushort_t As[64][72], Bs[64][72];
    const int b = blockIdx.x;
    const bool isval = b < 768;
    const ushort_t* A;
    const ushort_t* BT;
    const float* bias;
    int bm, bn;
    if (isval) { A = Ab; BT = WvT; bias = b_val;  bm = (b >> 2) * 64; bn = (b & 3) * 64; }
    else { int t = b - 768; A = Qb; BT = WcT; bias = bcomb; bm = (t / 6) * 64; bn = (t % 6) * 64; }

    f32x4 acc[2][2];
#pragma unroll
    for (int m = 0; m < 2; ++m)
#pragma unroll
        for (int n = 0; n < 2; ++n) acc[m][n] = (f32x4)0.f;

    mm_core(A, BT, bm, bn, As, Bs, acc);

    const int lane = threadIdx.x & 63, wave = threadIdx.x >> 6;
    const int wr = wave >> 1, wc = wave & 1;
    const int lr = lane & 15, rg = (lane >> 4) * 4;
#pragma unroll
    for (int n = 0; n < 2; ++n) {
        const int col = bn + wc * 32 + n * 16 + lr;
        const float bb = bias[col];
#pragma unroll
        for (int m = 0; m < 2; ++m)
#pragma unroll
            for (int rr = 0; rr < 4; ++rr) {
                const int row = bm + wr * 32 + m * 16 + rg + rr;
                if (row >= QTOT) continue;
                const float v = acc[m][n][rr] + bb;
                if (isval)            projb[(size_t)row * 256 + col] = f2b(v);
                else if (col < 256)   offb [(size_t)row * 256 + col] = f2b(v);
                else                  logitf[(size_t)row * 128 + col - 256] = v;
            }
    }
}

// Output projection: A = outpre bf16, C = f32 d_out.
__global__ __launch_bounds__(256) void gemm_o(
    const ushort_t* __restrict__ Ab, const ushort_t* __restrict__ WoT,
    const float* __restrict__ b_out, float* __restrict__ out)
{
    __shared__ ushort_t As[64][72], Bs[64][72];
    const int b = blockIdx.x;
    const int bm = (b >> 2) * 64, bn = (b & 3) * 64;

    f32x4 acc[2][2];
#pragma unroll
    for (int m = 0; m < 2; ++m)
#pragma unroll
        for (int n = 0; n < 2; ++n) acc[m][n] = (f32x4)0.f;

    mm_core(Ab, WoT, bm, bn, As, Bs, acc);

    const int lane = threadIdx.x & 63, wave = threadIdx.x >> 6;
    const int wr = wave >> 1, wc = wave & 1;
    const int lr = lane & 15, rg = (lane >> 4) * 4;
#pragma unroll
    for (int n = 0; n < 2; ++n) {
        const int col = bn + wc * 32 + n * 16 + lr;
        const float bb = b_out[col];
#pragma unroll
        for (int m = 0; m < 2; ++m)
#pragma unroll
            for (int rr = 0; rr < 4; ++rr) {
                const int row = bm + wr * 32 + m * 16 + rg + rr;
                if (row < QTOT) out[(size_t)row * 256 + col] = acc[m][n][rr] + bb;
            }
    }
}

// ---------------------------------------------------------------------------
// Softmax + bilinear sampling. Block = 1 query (XCD-swizzled).
// Phase 1 (128 thr): per-(head,point) softmax-folded corner weights + indices.
// Phase 2: 8 heads x 32 lanes; lane = 4 channels (dwordx2 gathers); 4 lane-
// quarters split the 16 points; shfl_xor(8)+shfl_xor(16) reduce.
// ---------------------------------------------------------------------------
__global__ __launch_bounds__(256) void sample3(
    const float* __restrict__ rp, const ushort_t* __restrict__ offb,
    const float* __restrict__ logitf, const ushort_t* __restrict__ projb,
    const int* __restrict__ sp, const int* __restrict__ lsi,
    ushort_t* __restrict__ outpre)
{
    const int bid = blockIdx.x;
    const int q = (bid & 7) * (QTOT / 8) + (bid >> 3);
    const int tid = threadIdx.x;

    __shared__ int   s_idx[128][4];
    __shared__ float s_w[128][4];

    if (tid < 128) {
        const int l = (tid >> 2) & 3;
        float logit = logitf[(size_t)q * 128 + tid];
        float mx = logit;
#pragma unroll
        for (int d = 1; d < 16; d <<= 1) mx = fmaxf(mx, __shfl_xor(mx, d));
        float e = __expf(logit - mx);
        float s = e;
#pragma unroll
        for (int d = 1; d < 16; d <<= 1) s += __shfl_xor(s, d);
        const float aw = e / s;

        const unsigned opk = *(const unsigned*)&offb[(size_t)q * 256 + tid * 2];
        const float ox = __uint_as_float(opk << 16);
        const float oy = __uint_as_float(opk & 0xffff0000u);

        const int Hl = sp[l * 2], Wl = sp[l * 2 + 1], st = lsi[l];
        const float rx = rp[((size_t)q * 4 + l) * 2 + 0];
        const float ry = rp[((size_t)q * 4 + l) * 2 + 1];

        const float x = rx * (float)Wl + ox - 0.5f;
        const float y = ry * (float)Hl + oy - 0.5f;
        const float xf = floorf(x), yf = floorf(y);
        const int x0 = (int)xf, y0 = (int)yf;
        const float lx = x - xf, ly = y - yf;

        const bool vx0 = (x0 >= 0) && (x0 < Wl);
        const bool vx1 = (x0 + 1 >= 0) && (x0 + 1 < Wl);
        const bool vy0 = (y0 >= 0) && (y0 < Hl);
        const bool vy1 = (y0 + 1 >= 0) && (y0 + 1 < Hl);

        s_w[tid][0] = (vx0 && vy0) ? aw * (1.f - ly) * (1.f - lx) : 0.f;
        s_w[tid][1] = (vx1 && vy0) ? aw * (1.f - ly) * lx         : 0.f;
        s_w[tid][2] = (vx0 && vy1) ? aw * ly * (1.f - lx)         : 0.f;
        s_w[tid][3] = (vx1 && vy1) ? aw * ly * lx                 : 0.f;
        s_idx[tid][0] = (vx0 && vy0) ? st + y0 * Wl + x0           : 0;
        s_idx[tid][1] = (vx1 && vy0) ? st + y0 * Wl + x0 + 1       : 0;
        s_idx[tid][2] = (vx0 && vy1) ? st + (y0 + 1) * Wl + x0     : 0;
        s_idx[tid][3] = (vx1 && vy1) ? st + (y0 + 1) * Wl + x0 + 1 : 0;
    }
    __syncthreads();

    const int h = tid >> 5, qtr = (tid >> 3) & 3, c4 = tid & 7;
    const ushort_t* base = projb + h * 32 + c4 * 4;

    float a0 = 0.f, a1 = 0.f, a2 = 0.f, a3 = 0.f;
#pragma unroll
    for (int i = 0; i < 4; ++i) {
        const int slot = h * 16 + qtr * 4 + i;
        const int4   id4 = *(const int4*)s_idx[slot];
        const float4 w4  = *(const float4*)s_w[slot];
        uint2 v;
        v = *(const uint2*)(base + (size_t)id4.x * 256);
        a0 += w4.x * __uint_as_float(v.x << 16);
        a1 += w4.x * __uint_as_float(v.x & 0xffff0000u);
        a2 += w4.x * __uint_as_float(v.y << 16);
        a3 += w4.x * __uint_as_float(v.y & 0xffff0000u);
        v = *(const uint2*)(base + (size_t)id4.y * 256);
        a0 += w4.y * __uint_as_float(v.x << 16);
        a1 += w4.y * __uint_as_float(v.x & 0xffff0000u);
        a2 += w4.y * __uint_as_float(v.y << 16);
        a3 += w4.y * __uint_as_float(v.y & 0xffff0000u);
        v = *(const uint2*)(base + (size_t)id4.z * 256);
        a0 += w4.z * __uint_as_float(v.x << 16);
        a1 += w4.z * __uint_as_float(v.x & 0xffff0000u);
        a2 += w4.z * __uint_as_float(v.y << 16);
        a3 += w4.z * __uint_as_float(v.y & 0xffff0000u);
        v = *(const uint2*)(base + (size_t)id4.w * 256);
        a0 += w4.w * __uint_as_float(v.x << 16);
        a1 += w4.w * __uint_as_float(v.x & 0xffff0000u);
        a2 += w4.w * __uint_as_float(v.y << 16);
        a3 += w4.w * __uint_as_float(v.y & 0xffff0000u);
    }
    a0 += __shfl_xor(a0, 8);  a1 += __shfl_xor(a1, 8);
    a2 += __shfl_xor(a2, 8);  a3 += __shfl_xor(a3, 8);
    a0 += __shfl_xor(a0, 16); a1 += __shfl_xor(a1, 16);
    a2 += __shfl_xor(a2, 16); a3 += __shfl_xor(a3, 16);

    if ((tid & 24) == 0) {
        uint2 o;
        o.x = (unsigned)f2b(a0) | ((unsigned)f2b(a1) << 16);
        o.y = (unsigned)f2b(a2) | ((unsigned)f2b(a3) << 16);
        *(uint2*)&outpre[(size_t)q * 256 + h * 32 + c4 * 4] = o;
    }
}

// ---------------------------------------------------------------------------
extern "C" void kernel_launch(void* const* d_in, const int* in_sizes, int n_in,
                              void* d_out, int out_size, void* d_ws, size_t ws_size,
                              hipStream_t stream) {
    const float* query  = (const float*)d_in[0];
    const float* rp     = (const float*)d_in[1];
    const float* inflat = (const float*)d_in[2];
    const int*   sp     = (const int*)d_in[3];
    const int*   lsi    = (const int*)d_in[4];
    const float* W_off  = (const float*)d_in[5];
    const float* b_off  = (const float*)d_in[6];
    const float* W_attn = (const float*)d_in[7];
    const float* b_attn = (const float*)d_in[8];
    const float* W_val  = (const float*)d_in[9];
    const float* b_val  = (const float*)d_in[10];
    const float* W_out  = (const float*)d_in[11];
    const float* b_out  = (const float*)d_in[12];
    float* out = (float*)d_out;

    char* ws = (char*)d_ws;
    ushort_t* inflat_b = (ushort_t*)ws; ws += (size_t)HWTOT * 256 * 2;
    ushort_t* query_b  = (ushort_t*)ws; ws += (size_t)QTOT * 256 * 2;
    ushort_t* projb    = (ushort_t*)ws; ws += (size_t)HWTOT * 256 * 2;
    ushort_t* offb     = (ushort_t*)ws; ws += (size_t)QTOT * 256 * 2;
    float*    logitf   = (float*)ws;    ws += (size_t)QTOT * 128 * 4;
    ushort_t* outpre   = (ushort_t*)ws; ws += (size_t)QTOT * 256 * 2;
    ushort_t* WvT      = (ushort_t*)ws; ws += 65536 * 2;
    ushort_t* WcT      = (ushort_t*)ws; ws += 98304 * 2;
    ushort_t* WoT      = (ushort_t*)ws; ws += 65536 * 2;
    float*    bcomb    = (float*)ws;    ws += 384 * 4;

    dim3 blk(256);

    conv_kernel<<<dim3((2 * AEL + 229760 + 255) / 256), blk, 0, stream>>>(
        inflat, query, W_val, W_off, W_attn, W_out, b_off, b_attn,
        inflat_b, query_b, WvT, WcT, WoT, bcomb);

    gemm_vc<<<dim3(768 + 1152), blk, 0, stream>>>(
        inflat_b, query_b, WvT, WcT, b_val, bcomb, projb, offb, logitf);

    sample3<<<dim3(QTOT), blk, 0, stream>>>(rp, offb, logitf, projb, sp, lsi, outpre);

    gemm_o<<<dim3(768), blk, 0, stream>>>(outpre, WoT, b_out, out);
}

// Round 4
// 70.227 us; speedup vs baseline: 4.0687x; 1.0388x over previous
//
#include <hip/hip_runtime.h>

#define QTOT 12240
#define KD   256

typedef float f32x4 __attribute__((ext_vector_type(4)));
typedef short s16x8 __attribute__((ext_vector_type(8)));
typedef unsigned short ushort_t;

__device__ __forceinline__ unsigned short f2b(float x) {
    union { float f; unsigned u; } c; c.f = x;
    unsigned r = c.u + 0x7fffu + ((c.u >> 16) & 1u);
    return (unsigned short)(r >> 16);
}
// swizzled LDS byte offsets (XOR bits 4-6 of k-byte with row&7): ~2-way max
__device__ __forceinline__ int a_off(int row, int kb) { return row * 512 + (kb ^ ((row & 7) << 4)); }
__device__ __forceinline__ int b_off(int n,   int kb) { return n * 128 + (kb ^ ((n & 7) << 4)); }

// ---------------------------------------------------------------------------
// prep: weight transpose+bf16 (tiny), combined off/attn bias
// ---------------------------------------------------------------------------
__global__ __launch_bounds__(256) void prep(
    const float* __restrict__ W_val, const float* __restrict__ W_off,
    const float* __restrict__ W_attn, const float* __restrict__ W_out,
    const float* __restrict__ b_off, const float* __restrict__ b_attn,
    ushort_t* __restrict__ WvT, ushort_t* __restrict__ WcT,
    ushort_t* __restrict__ WoT, float* __restrict__ bcomb)
{
    int id = blockIdx.x * 256 + threadIdx.x;
    if (id < 65536) { int n = id >> 8, k = id & 255; WvT[id] = f2b(W_val[k * 256 + n]); }
    else if (id < 163840) {
        int t = id - 65536; int n = t >> 8, k = t & 255;
        float v = (n < 256) ? W_off[k * 256 + n] : W_attn[k * 128 + (n - 256)];
        WcT[t] = f2b(v);
    } else if (id < 229376) {
        int t = id - 163840; int n = t >> 8, k = t & 255;
        WoT[t] = f2b(W_out[k * 256 + n]);
    } else if (id < 229760) {
        int t = id - 229376; bcomb[t] = (t < 256) ? b_off[t] : b_attn[t - 256];
    }
}

// ---------------------------------------------------------------------------
// B-tile stage: Bs[n][128B] holds W^T[n][k0..k0+63] bf16, source-swizzled.
// ---------------------------------------------------------------------------
template<int NF>
__device__ __forceinline__ void stageB(const ushort_t* __restrict__ WT, int k0, char* Bs) {
    const int tid = threadIdx.x;
#pragma unroll
    for (int e = 0; e < NF * 2; ++e) {
        int u = e * 256 + tid;
        int n = u >> 3, j = u & 7, js = j ^ (n & 7);
        s16x8 v = *(const s16x8*)(WT + (size_t)n * KD + k0 + js * 8);
        *(s16x8*)(Bs + n * 128 + j * 16) = v;
    }
}

// MFMA main loop: full-K A panel in LDS, per-kstep B tiles, wave = 32 x NF*16.
template<int NF>
__device__ __forceinline__ void mm_full(const ushort_t* __restrict__ WT,
                                        char* As, char* Bs, f32x4 (&acc)[2][NF])
{
    const int tid = threadIdx.x, lane = tid & 63, wc = tid >> 6;
    const int lr = lane & 15, g8 = (lane >> 4) * 8;
    for (int k0 = 0; k0 < KD; k0 += 64) {
        __syncthreads();
#pragma unroll
        for (int kk = 0; kk < 2; ++kk) {
            const int kbB = (kk * 32 + g8) * 2;
            const int kbA = (k0 + kk * 32 + g8) * 2;
            s16x8 af0 = *(const s16x8*)(As + a_off(lr, kbA));
            s16x8 af1 = *(const s16x8*)(As + a_off(16 + lr, kbA));
#pragma unroll
            for (int n = 0; n < NF; ++n) {
                s16x8 bf = *(const s16x8*)(Bs + b_off(wc * NF * 16 + n * 16 + lr, kbB));
                acc[0][n] = __builtin_amdgcn_mfma_f32_16x16x32_bf16(af0, bf, acc[0][n], 0, 0, 0);
                acc[1][n] = __builtin_amdgcn_mfma_f32_16x16x32_bf16(af1, bf, acc[1][n], 0, 0, 0);
            }
        }
        __syncthreads();
        if (k0 < 192) stageB<NF>(WT, k0 + 64, Bs);
    }
}

// ---------------------------------------------------------------------------
// gemm1: blocks 0..382 value-proj (N=256), 383..765 off/attn-proj (N=384).
// BM=32; A (f32) converted bf16 once into LDS.
// ---------------------------------------------------------------------------
__global__ __launch_bounds__(256) void gemm1(
    const float* __restrict__ inflat, const float* __restrict__ query,
    const ushort_t* __restrict__ WvT, const ushort_t* __restrict__ WcT,
    const float* __restrict__ b_val, const float* __restrict__ bcomb,
    ushort_t* __restrict__ projb, ushort_t* __restrict__ offb,
    float* __restrict__ logitf)
{
    __shared__ char smem[16384 + 49152];
    char* As = smem; char* Bs = smem + 16384;
    const int b = blockIdx.x;
    const bool isval = b < 383;
    const int bm = (isval ? b : b - 383) * 32;
    const float* A = isval ? inflat : query;

    {   // stage A panel: 32 rows x 256 k, f32 -> bf16
        const int row = threadIdx.x >> 3, c0 = (threadIdx.x & 7) * 32;
        const int grow = bm + row;
        float4 f[8];
        if (grow < QTOT) {
            const float4* s = (const float4*)(A + (size_t)grow * KD + c0);
#pragma unroll
            for (int i = 0; i < 8; ++i) f[i] = s[i];
        } else {
#pragma unroll
            for (int i = 0; i < 8; ++i) f[i] = make_float4(0.f, 0.f, 0.f, 0.f);
        }
#pragma unroll
        for (int i = 0; i < 4; ++i) {
            s16x8 v;
            v[0] = f2b(f[2*i].x);   v[1] = f2b(f[2*i].y);
            v[2] = f2b(f[2*i].z);   v[3] = f2b(f[2*i].w);
            v[4] = f2b(f[2*i+1].x); v[5] = f2b(f[2*i+1].y);
            v[6] = f2b(f[2*i+1].z); v[7] = f2b(f[2*i+1].w);
            *(s16x8*)(As + a_off(row, (c0 + i * 8) * 2)) = v;
        }
    }

    const int lane = threadIdx.x & 63, wc = threadIdx.x >> 6;
    const int lr = lane & 15, rg = (lane >> 4) * 4;

    if (isval) {
        f32x4 acc[2][4];
#pragma unroll
        for (int m = 0; m < 2; ++m)
#pragma unroll
            for (int n = 0; n < 4; ++n) acc[m][n] = (f32x4)0.f;
        stageB<4>(WvT, 0, Bs);
        mm_full<4>(WvT, As, Bs, acc);
#pragma unroll
        for (int n = 0; n < 4; ++n) {
            const int col = wc * 64 + n * 16 + lr;
            const float bb = b_val[col];
#pragma unroll
            for (int m = 0; m < 2; ++m)
#pragma unroll
                for (int rr = 0; rr < 4; ++rr) {
                    const int row = bm + m * 16 + rg + rr;
                    if (row < QTOT) projb[(size_t)row * 256 + col] = f2b(acc[m][n][rr] + bb);
                }
        }
    } else {
        f32x4 acc[2][6];
#pragma unroll
        for (int m = 0; m < 2; ++m)
#pragma unroll
            for (int n = 0; n < 6; ++n) acc[m][n] = (f32x4)0.f;
        stageB<6>(WcT, 0, Bs);
        mm_full<6>(WcT, As, Bs, acc);
#pragma unroll
        for (int n = 0; n < 6; ++n) {
            const int col = wc * 96 + n * 16 + lr;
            const float bb = bcomb[col];
#pragma unroll
            for (int m = 0; m < 2; ++m)
#pragma unroll
                for (int rr = 0; rr < 4; ++rr) {
                    const int row = bm + m * 16 + rg + rr;
                    if (row >= QTOT) continue;
                    const float v = acc[m][n][rr] + bb;
                    if (col < 256) offb[(size_t)row * 256 + col] = f2b(v);
                    else           logitf[(size_t)row * 128 + col - 256] = v;
                }
        }
    }
}

// ---------------------------------------------------------------------------
// sample: 2 queries per block. Phase1: 2x128 threads -> per-(head,point)
// softmax-folded corner weights + byte-offset indices. Phase2: 128 thr/query,
// lane = 8 channels (dwordx4), 4 lane-quarters split 16 points.
// ---------------------------------------------------------------------------
__global__ __launch_bounds__(256) void sample4(
    const float* __restrict__ rp, const ushort_t* __restrict__ offb,
    const float* __restrict__ logitf, const ushort_t* __restrict__ projb,
    const int* __restrict__ sp, const int* __restrict__ lsi,
    ushort_t* __restrict__ outpre)
{
    const int bid = blockIdx.x;
    const int qpair = (bid & 7) * 765 + (bid >> 3);     // 6120 = 8*765 bijective
    const int tid = threadIdx.x;
    const int qi = tid >> 7;
    const int q = qpair * 2 + qi;

    __shared__ int   s_idx[256][4];
    __shared__ float s_w[256][4];

    {   // phase 1: t = index within query's 128 (head,point) slots
        const int t = tid & 127;
        const int l = (t >> 2) & 3;
        float logit = logitf[(size_t)q * 128 + t];
        float mx = logit;
#pragma unroll
        for (int d = 1; d < 16; d <<= 1) mx = fmaxf(mx, __shfl_xor(mx, d));
        float e = __expf(logit - mx);
        float s = e;
#pragma unroll
        for (int d = 1; d < 16; d <<= 1) s += __shfl_xor(s, d);
        const float aw = e / s;

        const unsigned opk = *(const unsigned*)&offb[(size_t)q * 256 + t * 2];
        const float ox = __uint_as_float(opk << 16);
        const float oy = __uint_as_float(opk & 0xffff0000u);

        const int Hl = sp[l * 2], Wl = sp[l * 2 + 1], st = lsi[l];
        const float rx = rp[((size_t)q * 4 + l) * 2 + 0];
        const float ry = rp[((size_t)q * 4 + l) * 2 + 1];

        const float x = rx * (float)Wl + ox - 0.5f;
        const float y = ry * (float)Hl + oy - 0.5f;
        const float xf = floorf(x), yf = floorf(y);
        const int x0 = (int)xf, y0 = (int)yf;
        const float lx = x - xf, ly = y - yf;

        const bool vx0 = (x0 >= 0) && (x0 < Wl);
        const bool vx1 = (x0 + 1 >= 0) && (x0 + 1 < Wl);
        const bool vy0 = (y0 >= 0) && (y0 < Hl);
        const bool vy1 = (y0 + 1 >= 0) && (y0 + 1 < Hl);

        s_w[tid][0] = (vx0 && vy0) ? aw * (1.f - ly) * (1.f - lx) : 0.f;
        s_w[tid][1] = (vx1 && vy0) ? aw * (1.f - ly) * lx         : 0.f;
        s_w[tid][2] = (vx0 && vy1) ? aw * ly * (1.f - lx)         : 0.f;
        s_w[tid][3] = (vx1 && vy1) ? aw * ly * lx                 : 0.f;
        s_idx[tid][0] = (vx0 && vy0) ? (st + y0 * Wl + x0) * 512           : 0;
        s_idx[tid][1] = (vx1 && vy0) ? (st + y0 * Wl + x0 + 1) * 512       : 0;
        s_idx[tid][2] = (vx0 && vy1) ? (st + (y0 + 1) * Wl + x0) * 512     : 0;
        s_idx[tid][3] = (vx1 && vy1) ? (st + (y0 + 1) * Wl + x0 + 1) * 512 : 0;
    }
    __syncthreads();

    const int tt = tid & 127;
    const int h = tt >> 4, qtr = (tt >> 2) & 3, c8 = tt & 3;
    const char* basec = (const char*)projb + (h * 32 + c8 * 8) * 2;

    float a0 = 0, a1 = 0, a2 = 0, a3 = 0, a4 = 0, a5 = 0, a6 = 0, a7 = 0;
#pragma unroll
    for (int p = 0; p < 4; ++p) {
        const int slot = qi * 128 + h * 16 + qtr * 4 + p;
        const int4   id4 = *(const int4*)s_idx[slot];
        const float4 w4  = *(const float4*)s_w[slot];
#pragma unroll
        for (int c = 0; c < 4; ++c) {
            const int   id = (c == 0) ? id4.x : (c == 1) ? id4.y : (c == 2) ? id4.z : id4.w;
            const float w  = (c == 0) ? w4.x  : (c == 1) ? w4.y  : (c == 2) ? w4.z  : w4.w;
            const uint4 v = *(const uint4*)(basec + id);
            a0 += w * __uint_as_float(v.x << 16);
            a1 += w * __uint_as_float(v.x & 0xffff0000u);
            a2 += w * __uint_as_float(v.y << 16);
            a3 += w * __uint_as_float(v.y & 0xffff0000u);
            a4 += w * __uint_as_float(v.z << 16);
            a5 += w * __uint_as_float(v.z & 0xffff0000u);
            a6 += w * __uint_as_float(v.w << 16);
            a7 += w * __uint_as_float(v.w & 0xffff0000u);
        }
    }
    a0 += __shfl_xor(a0, 4); a1 += __shfl_xor(a1, 4);
    a2 += __shfl_xor(a2, 4); a3 += __shfl_xor(a3, 4);
    a4 += __shfl_xor(a4, 4); a5 += __shfl_xor(a5, 4);
    a6 += __shfl_xor(a6, 4); a7 += __shfl_xor(a7, 4);
    a0 += __shfl_xor(a0, 8); a1 += __shfl_xor(a1, 8);
    a2 += __shfl_xor(a2, 8); a3 += __shfl_xor(a3, 8);
    a4 += __shfl_xor(a4, 8); a5 += __shfl_xor(a5, 8);
    a6 += __shfl_xor(a6, 8); a7 += __shfl_xor(a7, 8);

    if (qtr == 0) {
        uint4 o;
        o.x = (unsigned)f2b(a0) | ((unsigned)f2b(a1) << 16);
        o.y = (unsigned)f2b(a2) | ((unsigned)f2b(a3) << 16);
        o.z = (unsigned)f2b(a4) | ((unsigned)f2b(a5) << 16);
        o.w = (unsigned)f2b(a6) | ((unsigned)f2b(a7) << 16);
        *(uint4*)&outpre[(size_t)q * 256 + h * 32 + c8 * 8] = o;
    }
}

// ---------------------------------------------------------------------------
// gemm_o: BM=16, grid 765 (exact). A = outpre bf16, out = f32.
// ---------------------------------------------------------------------------
__global__ __launch_bounds__(256) void gemm_o(
    const ushort_t* __restrict__ Ab, const ushort_t* __restrict__ WoT,
    const float* __restrict__ b_out, float* __restrict__ out)
{
    __shared__ char smem[8192 + 32768];
    char* As = smem; char* Bs = smem + 8192;
    const int bm = blockIdx.x * 16;

    {   // stage A: 16 rows x 256 k bf16
        const int row = threadIdx.x >> 4, cu = (threadIdx.x & 15) * 16;
        const s16x8* s = (const s16x8*)(Ab + (size_t)(bm + row) * KD + cu);
        s16x8 v0 = s[0], v1 = s[1];
        *(s16x8*)(As + a_off(row, cu * 2))      = v0;
        *(s16x8*)(As + a_off(row, cu * 2 + 16)) = v1;
    }

    f32x4 acc[4];
#pragma unroll
    for (int n = 0; n < 4; ++n) acc[n] = (f32x4)0.f;
    stageB<4>(WoT, 0, Bs);

    const int tid = threadIdx.x, lane = tid & 63, wc = tid >> 6;
    const int lr = lane & 15, g8 = (lane >> 4) * 8;
    for (int k0 = 0; k0 < KD; k0 += 64) {
        __syncthreads();
#pragma unroll
        for (int kk = 0; kk < 2; ++kk) {
            const int kbB = (kk * 32 + g8) * 2;
            const int kbA = (k0 + kk * 32 + g8) * 2;
            s16x8 af = *(const s16x8*)(As + a_off(lr, kbA));
#pragma unroll
            for (int n = 0; n < 4; ++n) {
                s16x8 bf = *(const s16x8*)(Bs + b_off(wc * 64 + n * 16 + lr, kbB));
                acc[n] = __builtin_amdgcn_mfma_f32_16x16x32_bf16(af, bf, acc[n], 0, 0, 0);
            }
        }
        __syncthreads();
        if (k0 < 192) stageB<4>(WoT, k0 + 64, Bs);
    }

    const int rg = (lane >> 4) * 4;
#pragma unroll
    for (int n = 0; n < 4; ++n) {
        const int col = wc * 64 + n * 16 + lr;
        const float bb = b_out[col];
#pragma unroll
        for (int rr = 0; rr < 4; ++rr) {
            const int row = bm + rg + rr;
            out[(size_t)row * 256 + col] = acc[n][rr] + bb;
        }
    }
}

// ---------------------------------------------------------------------------
extern "C" void kernel_launch(void* const* d_in, const int* in_sizes, int n_in,
                              void* d_out, int out_size, void* d_ws, size_t ws_size,
                              hipStream_t stream) {
    const float* query  = (const float*)d_in[0];
    const float* rp     = (const float*)d_in[1];
    const float* inflat = (const float*)d_in[2];
    const int*   sp     = (const int*)d_in[3];
    const int*   lsi    = (const int*)d_in[4];
    const float* W_off  = (const float*)d_in[5];
    const float* b_off  = (const float*)d_in[6];
    const float* W_attn = (const float*)d_in[7];
    const float* b_attn = (const float*)d_in[8];
    const float* W_val  = (const float*)d_in[9];
    const float* b_val  = (const float*)d_in[10];
    const float* W_out  = (const float*)d_in[11];
    const float* b_out  = (const float*)d_in[12];
    float* out = (float*)d_out;

    char* ws = (char*)d_ws;
    ushort_t* projb  = (ushort_t*)ws; ws += (size_t)QTOT * 256 * 2;
    ushort_t* offb   = (ushort_t*)ws; ws += (size_t)QTOT * 256 * 2;
    float*    logitf = (float*)ws;    ws += (size_t)QTOT * 128 * 4;
    ushort_t* outpre = (ushort_t*)ws; ws += (size_t)QTOT * 256 * 2;
    ushort_t* WvT    = (ushort_t*)ws; ws += 65536 * 2;
    ushort_t* WcT    = (ushort_t*)ws; ws += 98304 * 2;
    ushort_t* WoT    = (ushort_t*)ws; ws += 65536 * 2;
    float*    bcomb  = (float*)ws;    ws += 384 * 4;

    dim3 blk(256);

    prep<<<dim3(898), blk, 0, stream>>>(W_val, W_off, W_attn, W_out, b_off, b_attn,
                                        WvT, WcT, WoT, bcomb);

    gemm1<<<dim3(766), blk, 0, stream>>>(inflat, query, WvT, WcT, b_val, bcomb,
                                         projb, offb, logitf);

    sample4<<<dim3(6120), blk, 0, stream>>>(rp, offb, logitf, projb, sp, lsi, outpre);

    gemm_o<<<dim3(765), blk, 0, stream>>>(outpre, WoT, b_out, out);
}